// Round 7
// baseline (350.165 us; speedup 1.0000x reference)
//
#include <hip/hip_runtime.h>
#include <hip/hip_bf16.h>

#define HID 256
#define QD 64
#define NSEG 16
#define SLQ 2048
#define SLH 2048

typedef __attribute__((ext_vector_type(8))) short bf16x8;
typedef __attribute__((ext_vector_type(8))) __bf16 bf16x8b;
typedef __attribute__((ext_vector_type(4))) float f32x4;
typedef __attribute__((ext_vector_type(4))) short s16x4;

static __device__ __forceinline__ f32x4 mfma16(bf16x8 a, bf16x8 b, f32x4 c) {
  return __builtin_amdgcn_mfma_f32_16x16x32_bf16(
      __builtin_bit_cast(bf16x8b, a), __builtin_bit_cast(bf16x8b, b), c, 0, 0, 0);
}

static __device__ __forceinline__ short f2bf(float x) {
  union { float f; unsigned u; } v; v.f = x;
  unsigned r = v.u + 0x7fffu + ((v.u >> 16) & 1u);
  return (short)(r >> 16);
}

static __device__ __forceinline__ float bf2f(short s) {
  union { unsigned u; float f; } v;
  v.u = ((unsigned)(unsigned short)s) << 16;
  return v.f;
}

static __device__ __forceinline__ bf16x8 ld8f_bf(const float* p) {
  f32x4 a = *(const f32x4*)p;
  f32x4 b = *(const f32x4*)(p + 4);
  bf16x8 r;
  r[0] = f2bf(a[0]); r[1] = f2bf(a[1]); r[2] = f2bf(a[2]); r[3] = f2bf(a[3]);
  r[4] = f2bf(b[0]); r[5] = f2bf(b[1]); r[6] = f2bf(b[2]); r[7] = f2bf(b[3]);
  return r;
}

// Fused weight casts: WQ, WK, WV, fc_w -> bf16
__global__ __launch_bounds__(256) void cast4_kernel(const float* __restrict__ s0, short* __restrict__ d0, int n0,
                                                    const float* __restrict__ s1, short* __restrict__ d1, int n1,
                                                    const float* __restrict__ s2, short* __restrict__ d2, int n2,
                                                    const float* __restrict__ s3, short* __restrict__ d3, int n3) {
  int i = blockIdx.x * 256 + threadIdx.x;
  if (i < n0) d0[i] = f2bf(s0[i]);
  int j = i - n0;
  if (j >= 0 && j < n1) d1[j] = f2bf(s1[j]);
  int k = j - n1;
  if (k >= 0 && k < n2) d2[k] = f2bf(s2[k]);
  int l = k - n2;
  if (l >= 0 && l < n3) d3[l] = f2bf(s3[l]);
}

// qq = q @ WQ^T  -> bf16 [32768, 64]
__global__ __launch_bounds__(256) void proj_q_kernel(const float* __restrict__ q,
                                                     const short* __restrict__ wqb,
                                                     short* __restrict__ qq) {
  int wave = threadIdx.x >> 6, lane = threadIdx.x & 63;
  int quad = lane >> 4, l16 = lane & 15;
  int m0 = blockIdx.x * 64 + wave * 16;
  f32x4 acc[4];
#pragma unroll
  for (int n = 0; n < 4; ++n) acc[n] = f32x4{0.f, 0.f, 0.f, 0.f};
#pragma unroll
  for (int ks = 0; ks < 8; ++ks) {
    bf16x8 a = ld8f_bf(q + (size_t)(m0 + l16) * HID + ks * 32 + quad * 8);
#pragma unroll
    for (int n = 0; n < 4; ++n) {
      bf16x8 b = *(const bf16x8*)(wqb + (size_t)(n * 16 + l16) * HID + ks * 32 + quad * 8);
      acc[n] = mfma16(a, b, acc[n]);
    }
  }
#pragma unroll
  for (int n = 0; n < 4; ++n)
#pragma unroll
    for (int r = 0; r < 4; ++r)
      qq[(size_t)(m0 + quad * 4 + r) * QD + n * 16 + l16] = f2bf(acc[n][r]);
}

// k = h @ WK^T -> bf16 [32768,64] row-major
// v^T computed directly as WV @ h^T -> vt[seg][dv][tok] with coalesced stores
__global__ __launch_bounds__(256) void proj_hv_kernel(const float* __restrict__ h,
                                                      const short* __restrict__ wkb,
                                                      const short* __restrict__ wvb,
                                                      short* __restrict__ kb,
                                                      short* __restrict__ vt) {
  int wave = threadIdx.x >> 6, lane = threadIdx.x & 63;
  int quad = lane >> 4, l16 = lane & 15;
  int m0 = blockIdx.x * 64 + wave * 16;  // this wave's 16 token rows
  f32x4 kacc[4];
  f32x4 vacc[16];
#pragma unroll
  for (int n = 0; n < 4; ++n) kacc[n] = f32x4{0.f, 0.f, 0.f, 0.f};
#pragma unroll
  for (int n = 0; n < 16; ++n) vacc[n] = f32x4{0.f, 0.f, 0.f, 0.f};
#pragma unroll
  for (int ks = 0; ks < 8; ++ks) {
    bf16x8 a = ld8f_bf(h + (size_t)(m0 + l16) * HID + ks * 32 + quad * 8);
#pragma unroll
    for (int n = 0; n < 4; ++n) {
      bf16x8 b = *(const bf16x8*)(wkb + (size_t)(n * 16 + l16) * HID + ks * 32 + quad * 8);
      kacc[n] = mfma16(a, b, kacc[n]);
    }
#pragma unroll
    for (int mt = 0; mt < 16; ++mt) {
      bf16x8 wf = *(const bf16x8*)(wvb + (size_t)(mt * 16 + l16) * HID + ks * 32 + quad * 8);
      vacc[mt] = mfma16(wf, a, vacc[mt]);
    }
  }
#pragma unroll
  for (int n = 0; n < 4; ++n)
#pragma unroll
    for (int r = 0; r < 4; ++r)
      kb[(size_t)(m0 + quad * 4 + r) * QD + n * 16 + l16] = f2bf(kacc[n][r]);
  int seg = m0 >> 11;
  int tokl = m0 & 2047;
  short* vs = vt + (size_t)seg * HID * SLH;
#pragma unroll
  for (int mt = 0; mt < 16; ++mt)
#pragma unroll
    for (int r = 0; r < 4; ++r) {
      int dv = mt * 16 + quad * 4 + r;
      vs[(size_t)dv * SLH + tokl + l16] = f2bf(vacc[mt][r]);
    }
}

// Flash attention v5 + fused LN1.
// 512 blocks x 256 thr (4 waves). 64 q-rows/block. XCD swizzle: each XCD owns 2
// segments (2.5 MB K+V working set < 4 MiB L2). 2 blocks/CU = 2 barrier domains.
// Single-pass softmax (scores ~N(0,1), max ~5.7 sigma -> exp safe), P double
// buffer, 1 barrier/iter, K-frag register prefetch 1 iter ahead.
// Epilogue: LN(q + att) in-block, writes x as bf16.
__global__ __launch_bounds__(256, 2) void attn_kernel(const short* __restrict__ qq,
                                                      const short* __restrict__ kb,
                                                      const short* __restrict__ vt,
                                                      const float* __restrict__ qres,
                                                      const float* __restrict__ n0w,
                                                      const float* __restrict__ n0b,
                                                      short* __restrict__ xb) {
  __shared__ short p_lds[2][64][136];  // 34.8 KB; reused as o-staging in epilogue
  int wave = threadIdx.x >> 6, lane = threadIdx.x & 63;
  int quad = lane >> 4, l16 = lane & 15;
  int b = blockIdx.x;
  int xcd = b & 7, li = b >> 3;
  int seg = xcd * 2 + (li >> 5);
  int tile = li & 31;
  int qrow0 = seg * SLQ + tile * 64;
  const short* kseg = kb + (size_t)seg * SLH * QD;
  const short* vseg = vt + (size_t)seg * HID * SLH;

  // Q fragments (B-operand for S^T): this wave's 16 rows
  const short* qbase = qq + (size_t)(qrow0 + wave * 16 + l16) * QD + quad * 8;
  bf16x8 qf0 = *(const bf16x8*)qbase;
  bf16x8 qf1 = *(const bf16x8*)(qbase + 32);

  f32x4 o[4][4];
#pragma unroll
  for (int m = 0; m < 4; ++m)
#pragma unroll
    for (int n = 0; n < 4; ++n) o[m][n] = f32x4{0.f, 0.f, 0.f, 0.f};
  float lsum = 0.f;
  const float cexp = 0.125f * 1.44269504f;  // scale * log2(e)
  bf16x8 kpre[8][2];

#define LOADK(IT)                                                               \
  {                                                                             \
    int k0 = (IT) * 128;                                                        \
    _Pragma("unroll") for (int t = 0; t < 8; ++t) {                             \
      const short* kp = kseg + (size_t)(k0 + t * 16 + l16) * QD + quad * 8;     \
      kpre[t][0] = *(const bf16x8*)kp;                                          \
      kpre[t][1] = *(const bf16x8*)(kp + 32);                                   \
    }                                                                           \
  }

#define S_PHASE(BUF)                                                            \
  {                                                                             \
    f32x4 s[8];                                                                 \
    _Pragma("unroll") for (int t = 0; t < 8; ++t) {                             \
      f32x4 a = f32x4{0.f, 0.f, 0.f, 0.f};                                      \
      a = mfma16(kpre[t][0], qf0, a);                                           \
      a = mfma16(kpre[t][1], qf1, a);                                           \
      s[t] = a;                                                                 \
    }                                                                           \
    _Pragma("unroll") for (int t = 0; t < 8; ++t) {                             \
      float p0 = __builtin_amdgcn_exp2f(s[t][0] * cexp);                        \
      float p1 = __builtin_amdgcn_exp2f(s[t][1] * cexp);                        \
      float p2 = __builtin_amdgcn_exp2f(s[t][2] * cexp);                        \
      float p3 = __builtin_amdgcn_exp2f(s[t][3] * cexp);                        \
      lsum += (p0 + p1) + (p2 + p3);                                            \
      s16x4 pk;                                                                 \
      pk[0] = f2bf(p0); pk[1] = f2bf(p1); pk[2] = f2bf(p2); pk[3] = f2bf(p3);   \
      *(s16x4*)&p_lds[BUF][wave * 16 + l16][t * 16 + quad * 4] = pk;            \
    }                                                                           \
  }

#define PV_PHASE(IT, BUF)                                                       \
  {                                                                             \
    int k0 = (IT) * 128;                                                        \
    _Pragma("unroll") for (int ks = 0; ks < 4; ++ks) {                          \
      bf16x8 pf[4];                                                             \
      _Pragma("unroll") for (int m = 0; m < 4; ++m)                             \
        pf[m] = *(const bf16x8*)&p_lds[BUF][m * 16 + l16][ks * 32 + quad * 8];  \
      _Pragma("unroll") for (int n = 0; n < 4; ++n) {                           \
        const short* vp = vseg + (size_t)(wave * 64 + n * 16 + l16) * SLH +     \
                          k0 + ks * 32 + quad * 8;                              \
        bf16x8 vf = *(const bf16x8*)vp;                                         \
        _Pragma("unroll") for (int m = 0; m < 4; ++m)                           \
          o[m][n] = mfma16(pf[m], vf, o[m][n]);                                 \
      }                                                                         \
    }                                                                           \
  }

  LOADK(0)
  S_PHASE(0)
  LOADK(1)
  __syncthreads();
#pragma unroll 1
  for (int it = 1; it < 16; ++it) {
    S_PHASE(it & 1)
    if (it < 15) LOADK(it + 1)
    PV_PHASE(it - 1, (it - 1) & 1)
    __syncthreads();
  }
  PV_PHASE(15, 1)

  // row-sum: lane's partial covers its quad's k-cols for q-row wave*16+l16
  lsum += __shfl_xor(lsum, 16);
  lsum += __shfl_xor(lsum, 32);
  float linv = 1.f / lsum;  // for row wave*16 + l16 (all quads have it)

  __syncthreads();  // all PV LDS reads done before o-staging overwrites p_lds
  // stage raw O as bf16 into reused LDS: ob[row][dv], row stride 264
  short (*ob)[264] = (short(*)[264]) & p_lds[0][0][0];  // 64*264*2 = 33792 B
#pragma unroll
  for (int m = 0; m < 4; ++m)
#pragma unroll
    for (int n = 0; n < 4; ++n)
#pragma unroll
      for (int r = 0; r < 4; ++r)
        ob[m * 16 + quad * 4 + r][wave * 64 + n * 16 + l16] = f2bf(o[m][n][r]);
  __syncthreads();

  // LN over full 256-dim rows: lane (quad,l16) handles row wave*16+l16 (linv in
  // reg!), dv chunk quad*64..+64.
  {
    int row = wave * 16 + l16;
    float y[64];
    float s1 = 0.f, s2 = 0.f;
    const float* qp = qres + (size_t)(qrow0 + row) * HID + quad * 64;
#pragma unroll
    for (int k = 0; k < 8; ++k) {
      bf16x8 ov = *(const bf16x8*)&ob[row][quad * 64 + k * 8];
      f32x4 qa = *(const f32x4*)(qp + k * 8);
      f32x4 qb = *(const f32x4*)(qp + k * 8 + 4);
#pragma unroll
      for (int j = 0; j < 4; ++j) {
        float yv = qa[j] + bf2f(ov[j]) * linv;
        y[k * 8 + j] = yv;
        s1 += yv; s2 += yv * yv;
      }
#pragma unroll
      for (int j = 0; j < 4; ++j) {
        float yv = qb[j] + bf2f(ov[4 + j]) * linv;
        y[k * 8 + 4 + j] = yv;
        s1 += yv; s2 += yv * yv;
      }
    }
    s1 += __shfl_xor(s1, 16); s2 += __shfl_xor(s2, 16);
    s1 += __shfl_xor(s1, 32); s2 += __shfl_xor(s2, 32);
    float mean = s1 * (1.f / HID);
    float var = s2 * (1.f / HID) - mean * mean;
    float rstd = rsqrtf(var + 1e-5f);
    short* xp = xb + (size_t)(qrow0 + row) * HID + quad * 64;
#pragma unroll
    for (int k = 0; k < 8; ++k) {
      f32x4 wa = *(const f32x4*)(n0w + quad * 64 + k * 8);
      f32x4 wb = *(const f32x4*)(n0w + quad * 64 + k * 8 + 4);
      f32x4 ba = *(const f32x4*)(n0b + quad * 64 + k * 8);
      f32x4 bb = *(const f32x4*)(n0b + quad * 64 + k * 8 + 4);
      s16x4 o0, o1;
#pragma unroll
      for (int j = 0; j < 4; ++j) {
        o0[j] = f2bf((y[k * 8 + j] - mean) * rstd * wa[j] + ba[j]);
        o1[j] = f2bf((y[k * 8 + 4 + j] - mean) * rstd * wb[j] + bb[j]);
      }
      *(s16x4*)(xp + k * 8) = o0;
      *(s16x4*)(xp + k * 8 + 4) = o1;
    }
  }
#undef LOADK
#undef S_PHASE
#undef PV_PHASE
}

// out = LN(x + relu(x@fc_w^T + fc_b)); x is bf16.
__global__ __launch_bounds__(256) void fc_ln_kernel(const short* __restrict__ xb,
                                                    const short* __restrict__ fwb,
                                                    const float* __restrict__ fcb,
                                                    const float* __restrict__ w1,
                                                    const float* __restrict__ b1,
                                                    float* __restrict__ out) {
  int wave = threadIdx.x >> 6, lane = threadIdx.x & 63;
  int quad = lane >> 4, l16 = lane & 15;
  int m0 = blockIdx.x * 64 + wave * 16;
  f32x4 acc[16];
#pragma unroll
  for (int n = 0; n < 16; ++n) acc[n] = f32x4{0.f, 0.f, 0.f, 0.f};
#pragma unroll
  for (int ks = 0; ks < 8; ++ks) {
    bf16x8 a = *(const bf16x8*)(xb + (size_t)(m0 + l16) * HID + ks * 32 + quad * 8);
#pragma unroll
    for (int n = 0; n < 16; ++n) {
      bf16x8 b = *(const bf16x8*)(fwb + (size_t)(n * 16 + l16) * HID + ks * 32 + quad * 8);
      acc[n] = mfma16(a, b, acc[n]);
    }
  }
#pragma unroll
  for (int r = 0; r < 4; ++r) {
    int row = m0 + quad * 4 + r;
    float yv[16];
    float s = 0.f, s2 = 0.f;
#pragma unroll
    for (int n = 0; n < 16; ++n) {
      int col = n * 16 + l16;
      float hres = acc[n][r] + fcb[col];
      hres = fmaxf(hres, 0.f);
      float y = bf2f(xb[(size_t)row * HID + col]) + hres;
      yv[n] = y;
      s += y;
      s2 += y * y;
    }
#pragma unroll
    for (int off = 1; off < 16; off <<= 1) {
      s += __shfl_xor(s, off);
      s2 += __shfl_xor(s2, off);
    }
    float mean = s * (1.f / HID);
    float var = s2 * (1.f / HID) - mean * mean;
    float rstd = rsqrtf(var + 1e-5f);
#pragma unroll
    for (int n = 0; n < 16; ++n) {
      int col = n * 16 + l16;
      out[(size_t)row * HID + col] = (yv[n] - mean) * rstd * w1[col] + b1[col];
    }
  }
}

extern "C" void kernel_launch(void* const* d_in, const int* in_sizes, int n_in,
                              void* d_out, int out_size, void* d_ws, size_t ws_size,
                              hipStream_t stream) {
  const float* q = (const float*)d_in[0];
  const float* h = (const float*)d_in[1];
  const float* WQ = (const float*)d_in[2];
  const float* WK = (const float*)d_in[3];
  const float* WV = (const float*)d_in[4];
  const float* fc_w = (const float*)d_in[5];
  const float* fc_b = (const float*)d_in[6];
  const float* n0w = (const float*)d_in[7];
  const float* n0b = (const float*)d_in[8];
  const float* n1w = (const float*)d_in[9];
  const float* n1b = (const float*)d_in[10];

  char* ws = (char*)d_ws;
  short* qq = (short*)(ws);                            //  4 MB  [0,4)
  short* kb = (short*)(ws + ((size_t)4 << 20));        //  4 MB  [4,8)
  short* vt = (short*)(ws + ((size_t)8 << 20));        // 16 MB  [8,24)
  short* xb = (short*)(ws + ((size_t)24 << 20));       // 16 MB  [24,40)
  short* wqb = (short*)(ws + ((size_t)40 << 20));
  short* wkb = (short*)(ws + ((size_t)40 << 20) + 32 * 1024);
  short* wvb = (short*)(ws + ((size_t)40 << 20) + 64 * 1024);
  short* fwb = (short*)(ws + ((size_t)40 << 20) + 192 * 1024);

  cast4_kernel<<<640, 256, 0, stream>>>(WQ, wqb, QD * HID, WK, wkb, QD * HID,
                                        WV, wvb, HID * HID, fc_w, fwb, HID * HID);
  proj_q_kernel<<<512, 256, 0, stream>>>(q, wqb, qq);
  proj_hv_kernel<<<512, 256, 0, stream>>>(h, wkb, wvb, kb, vt);
  attn_kernel<<<512, 256, 0, stream>>>(qq, kb, vt, q, n0w, n0b, xb);
  fc_ln_kernel<<<512, 256, 0, stream>>>(xb, fwb, fc_b, n1w, n1b, (float*)d_out);
}

// Round 8
// 337.117 us; speedup vs baseline: 1.0387x; 1.0387x over previous
//
#include <hip/hip_runtime.h>
#include <hip/hip_bf16.h>

#define HID 256
#define QD 64
#define NSEG 16
#define SLQ 2048
#define SLH 2048

typedef __attribute__((ext_vector_type(8))) short bf16x8;
typedef __attribute__((ext_vector_type(8))) __bf16 bf16x8b;
typedef __attribute__((ext_vector_type(4))) float f32x4;
typedef __attribute__((ext_vector_type(4))) short s16x4;

static __device__ __forceinline__ f32x4 mfma16(bf16x8 a, bf16x8 b, f32x4 c) {
  return __builtin_amdgcn_mfma_f32_16x16x32_bf16(
      __builtin_bit_cast(bf16x8b, a), __builtin_bit_cast(bf16x8b, b), c, 0, 0, 0);
}

static __device__ __forceinline__ short f2bf(float x) {
  union { float f; unsigned u; } v; v.f = x;
  unsigned r = v.u + 0x7fffu + ((v.u >> 16) & 1u);
  return (short)(r >> 16);
}

static __device__ __forceinline__ float bf2f(short s) {
  union { unsigned u; float f; } v;
  v.u = ((unsigned)(unsigned short)s) << 16;
  return v.f;
}

// Fused weight casts: WQ, WK, WV, fc_w -> bf16
__global__ __launch_bounds__(256) void cast4_kernel(const float* __restrict__ s0, short* __restrict__ d0, int n0,
                                                    const float* __restrict__ s1, short* __restrict__ d1, int n1,
                                                    const float* __restrict__ s2, short* __restrict__ d2, int n2,
                                                    const float* __restrict__ s3, short* __restrict__ d3, int n3) {
  int i = blockIdx.x * 256 + threadIdx.x;
  if (i < n0) d0[i] = f2bf(s0[i]);
  int j = i - n0;
  if (j >= 0 && j < n1) d1[j] = f2bf(s1[j]);
  int k = j - n1;
  if (k >= 0 && k < n2) d2[k] = f2bf(s2[k]);
  int l = k - n2;
  if (l >= 0 && l < n3) d3[l] = f2bf(s3[l]);
}

// qq = q @ WQ^T -> bf16 [32768, 64]. A-tile staged via LDS (coalesced reads).
__global__ __launch_bounds__(256) void proj_q_kernel(const float* __restrict__ q,
                                                     const short* __restrict__ wqb,
                                                     short* __restrict__ qq) {
  __shared__ short hb[64][264];  // pad 8 -> b128 frag reads at bank minimum
  int m0 = blockIdx.x * 64;
  // stage 64 rows x 256 cols fp32 -> bf16; each wave reads 1 KB contiguous
#pragma unroll
  for (int i = 0; i < 16; ++i) {
    int idx = i * 256 + threadIdx.x;
    int row = idx >> 6, col = (idx & 63) * 4;
    f32x4 v = *(const f32x4*)(q + (size_t)(m0 + row) * HID + col);
    s16x4 pk;
#pragma unroll
    for (int j = 0; j < 4; ++j) pk[j] = f2bf(v[j]);
    *(s16x4*)&hb[row][col] = pk;
  }
  __syncthreads();
  int wave = threadIdx.x >> 6, lane = threadIdx.x & 63;
  int quad = lane >> 4, l16 = lane & 15;
  f32x4 acc[4];
#pragma unroll
  for (int n = 0; n < 4; ++n) acc[n] = f32x4{0.f, 0.f, 0.f, 0.f};
#pragma unroll
  for (int ks = 0; ks < 8; ++ks) {
    bf16x8 a = *(const bf16x8*)&hb[wave * 16 + l16][ks * 32 + quad * 8];
#pragma unroll
    for (int n = 0; n < 4; ++n) {
      bf16x8 b = *(const bf16x8*)(wqb + (size_t)(n * 16 + l16) * HID + ks * 32 + quad * 8);
      acc[n] = mfma16(a, b, acc[n]);
    }
  }
#pragma unroll
  for (int n = 0; n < 4; ++n)
#pragma unroll
    for (int r = 0; r < 4; ++r)
      qq[(size_t)(m0 + wave * 16 + quad * 4 + r) * QD + n * 16 + l16] = f2bf(acc[n][r]);
}

// k = h @ WK^T -> kb row-major; v^T = WV @ h^T -> vt[seg][dv][tok].
// h-tile staged via LDS (coalesced reads); same LDS frag feeds both products.
__global__ __launch_bounds__(256) void proj_hv_kernel(const float* __restrict__ h,
                                                      const short* __restrict__ wkb,
                                                      const short* __restrict__ wvb,
                                                      short* __restrict__ kb,
                                                      short* __restrict__ vt) {
  __shared__ short hb[64][264];
  int m0 = blockIdx.x * 64;
#pragma unroll
  for (int i = 0; i < 16; ++i) {
    int idx = i * 256 + threadIdx.x;
    int row = idx >> 6, col = (idx & 63) * 4;
    f32x4 v = *(const f32x4*)(h + (size_t)(m0 + row) * HID + col);
    s16x4 pk;
#pragma unroll
    for (int j = 0; j < 4; ++j) pk[j] = f2bf(v[j]);
    *(s16x4*)&hb[row][col] = pk;
  }
  __syncthreads();
  int wave = threadIdx.x >> 6, lane = threadIdx.x & 63;
  int quad = lane >> 4, l16 = lane & 15;
  int mw = wave * 16;
  f32x4 kacc[4];
  f32x4 vacc[16];
#pragma unroll
  for (int n = 0; n < 4; ++n) kacc[n] = f32x4{0.f, 0.f, 0.f, 0.f};
#pragma unroll
  for (int n = 0; n < 16; ++n) vacc[n] = f32x4{0.f, 0.f, 0.f, 0.f};
#pragma unroll
  for (int ks = 0; ks < 8; ++ks) {
    bf16x8 a = *(const bf16x8*)&hb[mw + l16][ks * 32 + quad * 8];
#pragma unroll
    for (int n = 0; n < 4; ++n) {
      bf16x8 b = *(const bf16x8*)(wkb + (size_t)(n * 16 + l16) * HID + ks * 32 + quad * 8);
      kacc[n] = mfma16(a, b, kacc[n]);
    }
#pragma unroll
    for (int mt = 0; mt < 16; ++mt) {
      bf16x8 wf = *(const bf16x8*)(wvb + (size_t)(mt * 16 + l16) * HID + ks * 32 + quad * 8);
      vacc[mt] = mfma16(wf, a, vacc[mt]);  // D[m=dv][n=tok] = WV @ h^T
    }
  }
#pragma unroll
  for (int n = 0; n < 4; ++n)
#pragma unroll
    for (int r = 0; r < 4; ++r)
      kb[(size_t)(m0 + mw + quad * 4 + r) * QD + n * 16 + l16] = f2bf(kacc[n][r]);
  int seg = (m0 + mw) >> 11;
  int tokl = (m0 + mw) & 2047;
  short* vs = vt + (size_t)seg * HID * SLH;
#pragma unroll
  for (int mt = 0; mt < 16; ++mt)
#pragma unroll
    for (int r = 0; r < 4; ++r) {
      int dv = mt * 16 + quad * 4 + r;
      vs[(size_t)dv * SLH + tokl + l16] = f2bf(vacc[mt][r]);
    }
}

// Flash attention v5 + fused LN1. (UNCHANGED from round 7 — known-pass.)
// 512 blocks x 256 thr (4 waves). 64 q-rows/block. XCD swizzle: each XCD owns 2
// segments. Single-pass softmax, P double buffer, 1 barrier/iter, K-frag
// register prefetch 1 iter ahead. NOTE: V-register prefetch across the barrier
// is POISON (r6: VGPR WAR vs in-flight loads miscompiles at this pressure).
__global__ __launch_bounds__(256, 2) void attn_kernel(const short* __restrict__ qq,
                                                      const short* __restrict__ kb,
                                                      const short* __restrict__ vt,
                                                      const float* __restrict__ qres,
                                                      const float* __restrict__ n0w,
                                                      const float* __restrict__ n0b,
                                                      short* __restrict__ xb) {
  __shared__ short p_lds[2][64][136];  // 34.8 KB; reused as o-staging in epilogue
  int wave = threadIdx.x >> 6, lane = threadIdx.x & 63;
  int quad = lane >> 4, l16 = lane & 15;
  int b = blockIdx.x;
  int xcd = b & 7, li = b >> 3;
  int seg = xcd * 2 + (li >> 5);
  int tile = li & 31;
  int qrow0 = seg * SLQ + tile * 64;
  const short* kseg = kb + (size_t)seg * SLH * QD;
  const short* vseg = vt + (size_t)seg * HID * SLH;

  const short* qbase = qq + (size_t)(qrow0 + wave * 16 + l16) * QD + quad * 8;
  bf16x8 qf0 = *(const bf16x8*)qbase;
  bf16x8 qf1 = *(const bf16x8*)(qbase + 32);

  f32x4 o[4][4];
#pragma unroll
  for (int m = 0; m < 4; ++m)
#pragma unroll
    for (int n = 0; n < 4; ++n) o[m][n] = f32x4{0.f, 0.f, 0.f, 0.f};
  float lsum = 0.f;
  const float cexp = 0.125f * 1.44269504f;  // scale * log2(e)
  bf16x8 kpre[8][2];

#define LOADK(IT)                                                               \
  {                                                                             \
    int k0 = (IT) * 128;                                                        \
    _Pragma("unroll") for (int t = 0; t < 8; ++t) {                             \
      const short* kp = kseg + (size_t)(k0 + t * 16 + l16) * QD + quad * 8;     \
      kpre[t][0] = *(const bf16x8*)kp;                                          \
      kpre[t][1] = *(const bf16x8*)(kp + 32);                                   \
    }                                                                           \
  }

#define S_PHASE(BUF)                                                            \
  {                                                                             \
    f32x4 s[8];                                                                 \
    _Pragma("unroll") for (int t = 0; t < 8; ++t) {                             \
      f32x4 a = f32x4{0.f, 0.f, 0.f, 0.f};                                      \
      a = mfma16(kpre[t][0], qf0, a);                                           \
      a = mfma16(kpre[t][1], qf1, a);                                           \
      s[t] = a;                                                                 \
    }                                                                           \
    _Pragma("unroll") for (int t = 0; t < 8; ++t) {                             \
      float p0 = __builtin_amdgcn_exp2f(s[t][0] * cexp);                        \
      float p1 = __builtin_amdgcn_exp2f(s[t][1] * cexp);                        \
      float p2 = __builtin_amdgcn_exp2f(s[t][2] * cexp);                        \
      float p3 = __builtin_amdgcn_exp2f(s[t][3] * cexp);                        \
      lsum += (p0 + p1) + (p2 + p3);                                            \
      s16x4 pk;                                                                 \
      pk[0] = f2bf(p0); pk[1] = f2bf(p1); pk[2] = f2bf(p2); pk[3] = f2bf(p3);   \
      *(s16x4*)&p_lds[BUF][wave * 16 + l16][t * 16 + quad * 4] = pk;            \
    }                                                                           \
  }

#define PV_PHASE(IT, BUF)                                                       \
  {                                                                             \
    int k0 = (IT) * 128;                                                        \
    _Pragma("unroll") for (int ks = 0; ks < 4; ++ks) {                          \
      bf16x8 pf[4];                                                             \
      _Pragma("unroll") for (int m = 0; m < 4; ++m)                             \
        pf[m] = *(const bf16x8*)&p_lds[BUF][m * 16 + l16][ks * 32 + quad * 8];  \
      _Pragma("unroll") for (int n = 0; n < 4; ++n) {                           \
        const short* vp = vseg + (size_t)(wave * 64 + n * 16 + l16) * SLH +     \
                          k0 + ks * 32 + quad * 8;                              \
        bf16x8 vf = *(const bf16x8*)vp;                                         \
        _Pragma("unroll") for (int m = 0; m < 4; ++m)                           \
          o[m][n] = mfma16(pf[m], vf, o[m][n]);                                 \
      }                                                                         \
    }                                                                           \
  }

  LOADK(0)
  S_PHASE(0)
  LOADK(1)
  __syncthreads();
#pragma unroll 1
  for (int it = 1; it < 16; ++it) {
    S_PHASE(it & 1)
    if (it < 15) LOADK(it + 1)
    PV_PHASE(it - 1, (it - 1) & 1)
    __syncthreads();
  }
  PV_PHASE(15, 1)

  lsum += __shfl_xor(lsum, 16);
  lsum += __shfl_xor(lsum, 32);
  float linv = 1.f / lsum;

  __syncthreads();
  short (*ob)[264] = (short(*)[264]) & p_lds[0][0][0];
#pragma unroll
  for (int m = 0; m < 4; ++m)
#pragma unroll
    for (int n = 0; n < 4; ++n)
#pragma unroll
      for (int r = 0; r < 4; ++r)
        ob[m * 16 + quad * 4 + r][wave * 64 + n * 16 + l16] = f2bf(o[m][n][r]);
  __syncthreads();

  {
    int row = wave * 16 + l16;
    float y[64];
    float s1 = 0.f, s2 = 0.f;
    const float* qp = qres + (size_t)(qrow0 + row) * HID + quad * 64;
#pragma unroll
    for (int k = 0; k < 8; ++k) {
      bf16x8 ov = *(const bf16x8*)&ob[row][quad * 64 + k * 8];
      f32x4 qa = *(const f32x4*)(qp + k * 8);
      f32x4 qb = *(const f32x4*)(qp + k * 8 + 4);
#pragma unroll
      for (int j = 0; j < 4; ++j) {
        float yv = qa[j] + bf2f(ov[j]) * linv;
        y[k * 8 + j] = yv;
        s1 += yv; s2 += yv * yv;
      }
#pragma unroll
      for (int j = 0; j < 4; ++j) {
        float yv = qb[j] + bf2f(ov[4 + j]) * linv;
        y[k * 8 + 4 + j] = yv;
        s1 += yv; s2 += yv * yv;
      }
    }
    s1 += __shfl_xor(s1, 16); s2 += __shfl_xor(s2, 16);
    s1 += __shfl_xor(s1, 32); s2 += __shfl_xor(s2, 32);
    float mean = s1 * (1.f / HID);
    float var = s2 * (1.f / HID) - mean * mean;
    float rstd = rsqrtf(var + 1e-5f);
    short* xp = xb + (size_t)(qrow0 + row) * HID + quad * 64;
#pragma unroll
    for (int k = 0; k < 8; ++k) {
      f32x4 wa = *(const f32x4*)(n0w + quad * 64 + k * 8);
      f32x4 wb = *(const f32x4*)(n0w + quad * 64 + k * 8 + 4);
      f32x4 ba = *(const f32x4*)(n0b + quad * 64 + k * 8);
      f32x4 bb = *(const f32x4*)(n0b + quad * 64 + k * 8 + 4);
      s16x4 o0, o1;
#pragma unroll
      for (int j = 0; j < 4; ++j) {
        o0[j] = f2bf((y[k * 8 + j] - mean) * rstd * wa[j] + ba[j]);
        o1[j] = f2bf((y[k * 8 + 4 + j] - mean) * rstd * wb[j] + bb[j]);
      }
      *(s16x4*)(xp + k * 8) = o0;
      *(s16x4*)(xp + k * 8 + 4) = o1;
    }
  }
#undef LOADK
#undef S_PHASE
#undef PV_PHASE
}

// out = LN(x + relu(x@fc_w^T + fc_b)); x (bf16) staged via LDS — coalesced
// reads, frags via ds_read_b128, residual from LDS (no global re-read).
__global__ __launch_bounds__(256) void fc_ln_kernel(const short* __restrict__ xb,
                                                    const short* __restrict__ fwb,
                                                    const float* __restrict__ fcb,
                                                    const float* __restrict__ w1,
                                                    const float* __restrict__ b1,
                                                    float* __restrict__ out) {
  __shared__ short xt[64][264];
  int m0 = blockIdx.x * 64;
  // stage 64 rows x 256 bf16 (32 KB); each wave reads 1 KB contiguous
#pragma unroll
  for (int i = 0; i < 8; ++i) {
    int idx = i * 256 + threadIdx.x;
    int row = idx >> 5, col = (idx & 31) * 8;
    bf16x8 v = *(const bf16x8*)(xb + (size_t)(m0 + row) * HID + col);
    *(bf16x8*)&xt[row][col] = v;
  }
  __syncthreads();
  int wave = threadIdx.x >> 6, lane = threadIdx.x & 63;
  int quad = lane >> 4, l16 = lane & 15;
  int mw = wave * 16;
  f32x4 acc[16];
#pragma unroll
  for (int n = 0; n < 16; ++n) acc[n] = f32x4{0.f, 0.f, 0.f, 0.f};
#pragma unroll
  for (int ks = 0; ks < 8; ++ks) {
    bf16x8 a = *(const bf16x8*)&xt[mw + l16][ks * 32 + quad * 8];
#pragma unroll
    for (int n = 0; n < 16; ++n) {
      bf16x8 b = *(const bf16x8*)(fwb + (size_t)(n * 16 + l16) * HID + ks * 32 + quad * 8);
      acc[n] = mfma16(a, b, acc[n]);
    }
  }
#pragma unroll
  for (int r = 0; r < 4; ++r) {
    int lrow = mw + quad * 4 + r;
    int row = m0 + lrow;
    float yv[16];
    float s = 0.f, s2 = 0.f;
#pragma unroll
    for (int n = 0; n < 16; ++n) {
      int col = n * 16 + l16;
      float hres = acc[n][r] + fcb[col];
      hres = fmaxf(hres, 0.f);
      float y = bf2f(xt[lrow][col]) + hres;
      yv[n] = y;
      s += y;
      s2 += y * y;
    }
#pragma unroll
    for (int off = 1; off < 16; off <<= 1) {
      s += __shfl_xor(s, off);
      s2 += __shfl_xor(s2, off);
    }
    float mean = s * (1.f / HID);
    float var = s2 * (1.f / HID) - mean * mean;
    float rstd = rsqrtf(var + 1e-5f);
#pragma unroll
    for (int n = 0; n < 16; ++n) {
      int col = n * 16 + l16;
      out[(size_t)row * HID + col] = (yv[n] - mean) * rstd * w1[col] + b1[col];
    }
  }
}

extern "C" void kernel_launch(void* const* d_in, const int* in_sizes, int n_in,
                              void* d_out, int out_size, void* d_ws, size_t ws_size,
                              hipStream_t stream) {
  const float* q = (const float*)d_in[0];
  const float* h = (const float*)d_in[1];
  const float* WQ = (const float*)d_in[2];
  const float* WK = (const float*)d_in[3];
  const float* WV = (const float*)d_in[4];
  const float* fc_w = (const float*)d_in[5];
  const float* fc_b = (const float*)d_in[6];
  const float* n0w = (const float*)d_in[7];
  const float* n0b = (const float*)d_in[8];
  const float* n1w = (const float*)d_in[9];
  const float* n1b = (const float*)d_in[10];

  char* ws = (char*)d_ws;
  short* qq = (short*)(ws);                            //  4 MB  [0,4)
  short* kb = (short*)(ws + ((size_t)4 << 20));        //  4 MB  [4,8)
  short* vt = (short*)(ws + ((size_t)8 << 20));        // 16 MB  [8,24)
  short* xb = (short*)(ws + ((size_t)24 << 20));       // 16 MB  [24,40)
  short* wqb = (short*)(ws + ((size_t)40 << 20));
  short* wkb = (short*)(ws + ((size_t)40 << 20) + 32 * 1024);
  short* wvb = (short*)(ws + ((size_t)40 << 20) + 64 * 1024);
  short* fwb = (short*)(ws + ((size_t)40 << 20) + 192 * 1024);

  cast4_kernel<<<640, 256, 0, stream>>>(WQ, wqb, QD * HID, WK, wkb, QD * HID,
                                        WV, wvb, HID * HID, fc_w, fwb, HID * HID);
  proj_q_kernel<<<512, 256, 0, stream>>>(q, wqb, qq);
  proj_hv_kernel<<<512, 256, 0, stream>>>(h, wkb, wvb, kb, vt);
  attn_kernel<<<512, 256, 0, stream>>>(qq, kb, vt, q, n0w, n0b, xb);
  fc_ln_kernel<<<512, 256, 0, stream>>>(xb, fwb, fc_b, n1w, n1b, (float*)d_out);
}

// Round 9
// 334.853 us; speedup vs baseline: 1.0457x; 1.0068x over previous
//
#include <hip/hip_runtime.h>
#include <hip/hip_bf16.h>

#define HID 256
#define QD 64
#define NSEG 16
#define SLQ 2048
#define SLH 2048

typedef __attribute__((ext_vector_type(8))) short bf16x8;
typedef __attribute__((ext_vector_type(8))) __bf16 bf16x8b;
typedef __attribute__((ext_vector_type(4))) float f32x4;
typedef __attribute__((ext_vector_type(4))) short s16x4;

// LDS-only barrier: completes this wave's LDS ops (lgkmcnt) and syncs, but does
// NOT drain outstanding global loads (vmcnt) the way __syncthreads() does.
// All cross-wave data in attn flows through LDS, so this is sufficient; global
// loads are wave-private and guarded by compiler-inserted vmcnt-before-use.
#define BAR_LDS() asm volatile("s_waitcnt lgkmcnt(0)\n\ts_barrier" ::: "memory")

static __device__ __forceinline__ f32x4 mfma16(bf16x8 a, bf16x8 b, f32x4 c) {
  return __builtin_amdgcn_mfma_f32_16x16x32_bf16(
      __builtin_bit_cast(bf16x8b, a), __builtin_bit_cast(bf16x8b, b), c, 0, 0, 0);
}

static __device__ __forceinline__ short f2bf(float x) {
  union { float f; unsigned u; } v; v.f = x;
  unsigned r = v.u + 0x7fffu + ((v.u >> 16) & 1u);
  return (short)(r >> 16);
}

static __device__ __forceinline__ float bf2f(short s) {
  union { unsigned u; float f; } v;
  v.u = ((unsigned)(unsigned short)s) << 16;
  return v.f;
}

// Fused weight casts: WQ, WK, WV, fc_w -> bf16
__global__ __launch_bounds__(256) void cast4_kernel(const float* __restrict__ s0, short* __restrict__ d0, int n0,
                                                    const float* __restrict__ s1, short* __restrict__ d1, int n1,
                                                    const float* __restrict__ s2, short* __restrict__ d2, int n2,
                                                    const float* __restrict__ s3, short* __restrict__ d3, int n3) {
  int i = blockIdx.x * 256 + threadIdx.x;
  if (i < n0) d0[i] = f2bf(s0[i]);
  int j = i - n0;
  if (j >= 0 && j < n1) d1[j] = f2bf(s1[j]);
  int k = j - n1;
  if (k >= 0 && k < n2) d2[k] = f2bf(s2[k]);
  int l = k - n2;
  if (l >= 0 && l < n3) d3[l] = f2bf(s3[l]);
}

// qq = q @ WQ^T -> bf16 [32768, 64]. A-tile staged via LDS (coalesced reads).
__global__ __launch_bounds__(256) void proj_q_kernel(const float* __restrict__ q,
                                                     const short* __restrict__ wqb,
                                                     short* __restrict__ qq) {
  __shared__ short hb[64][264];  // pad 8 -> b128 frag reads at bank minimum
  int m0 = blockIdx.x * 64;
  // stage 64 rows x 256 cols fp32 -> bf16; each wave reads 1 KB contiguous
#pragma unroll
  for (int i = 0; i < 16; ++i) {
    int idx = i * 256 + threadIdx.x;
    int row = idx >> 6, col = (idx & 63) * 4;
    f32x4 v = *(const f32x4*)(q + (size_t)(m0 + row) * HID + col);
    s16x4 pk;
#pragma unroll
    for (int j = 0; j < 4; ++j) pk[j] = f2bf(v[j]);
    *(s16x4*)&hb[row][col] = pk;
  }
  __syncthreads();
  int wave = threadIdx.x >> 6, lane = threadIdx.x & 63;
  int quad = lane >> 4, l16 = lane & 15;
  f32x4 acc[4];
#pragma unroll
  for (int n = 0; n < 4; ++n) acc[n] = f32x4{0.f, 0.f, 0.f, 0.f};
#pragma unroll
  for (int ks = 0; ks < 8; ++ks) {
    bf16x8 a = *(const bf16x8*)&hb[wave * 16 + l16][ks * 32 + quad * 8];
#pragma unroll
    for (int n = 0; n < 4; ++n) {
      bf16x8 b = *(const bf16x8*)(wqb + (size_t)(n * 16 + l16) * HID + ks * 32 + quad * 8);
      acc[n] = mfma16(a, b, acc[n]);
    }
  }
#pragma unroll
  for (int n = 0; n < 4; ++n)
#pragma unroll
    for (int r = 0; r < 4; ++r)
      qq[(size_t)(m0 + wave * 16 + quad * 4 + r) * QD + n * 16 + l16] = f2bf(acc[n][r]);
}

// k = h @ WK^T -> kb row-major; v^T = WV @ h^T -> vt[seg][dv][tok].
// h-tile staged via LDS (coalesced reads); same LDS frag feeds both products.
__global__ __launch_bounds__(256) void proj_hv_kernel(const float* __restrict__ h,
                                                      const short* __restrict__ wkb,
                                                      const short* __restrict__ wvb,
                                                      short* __restrict__ kb,
                                                      short* __restrict__ vt) {
  __shared__ short hb[64][264];
  int m0 = blockIdx.x * 64;
#pragma unroll
  for (int i = 0; i < 16; ++i) {
    int idx = i * 256 + threadIdx.x;
    int row = idx >> 6, col = (idx & 63) * 4;
    f32x4 v = *(const f32x4*)(h + (size_t)(m0 + row) * HID + col);
    s16x4 pk;
#pragma unroll
    for (int j = 0; j < 4; ++j) pk[j] = f2bf(v[j]);
    *(s16x4*)&hb[row][col] = pk;
  }
  __syncthreads();
  int wave = threadIdx.x >> 6, lane = threadIdx.x & 63;
  int quad = lane >> 4, l16 = lane & 15;
  int mw = wave * 16;
  f32x4 kacc[4];
  f32x4 vacc[16];
#pragma unroll
  for (int n = 0; n < 4; ++n) kacc[n] = f32x4{0.f, 0.f, 0.f, 0.f};
#pragma unroll
  for (int n = 0; n < 16; ++n) vacc[n] = f32x4{0.f, 0.f, 0.f, 0.f};
#pragma unroll
  for (int ks = 0; ks < 8; ++ks) {
    bf16x8 a = *(const bf16x8*)&hb[mw + l16][ks * 32 + quad * 8];
#pragma unroll
    for (int n = 0; n < 4; ++n) {
      bf16x8 b = *(const bf16x8*)(wkb + (size_t)(n * 16 + l16) * HID + ks * 32 + quad * 8);
      kacc[n] = mfma16(a, b, kacc[n]);
    }
#pragma unroll
    for (int mt = 0; mt < 16; ++mt) {
      bf16x8 wf = *(const bf16x8*)(wvb + (size_t)(mt * 16 + l16) * HID + ks * 32 + quad * 8);
      vacc[mt] = mfma16(wf, a, vacc[mt]);  // D[m=dv][n=tok] = WV @ h^T
    }
  }
#pragma unroll
  for (int n = 0; n < 4; ++n)
#pragma unroll
    for (int r = 0; r < 4; ++r)
      kb[(size_t)(m0 + mw + quad * 4 + r) * QD + n * 16 + l16] = f2bf(kacc[n][r]);
  int seg = (m0 + mw) >> 11;
  int tokl = (m0 + mw) & 2047;
  short* vs = vt + (size_t)seg * HID * SLH;
#pragma unroll
  for (int mt = 0; mt < 16; ++mt)
#pragma unroll
    for (int r = 0; r < 4; ++r) {
      int dv = mt * 16 + quad * 4 + r;
      vs[(size_t)dv * SLH + tokl + l16] = f2bf(vacc[mt][r]);
    }
}

// Flash attention v5 + fused LN1, with LDS-only barriers (no vmcnt drain).
// 512 blocks x 256 thr (4 waves). 64 q-rows/block. XCD swizzle: each XCD owns 2
// segments. Single-pass softmax, P double buffer, 1 barrier/iter, K-frag
// register prefetch 1 iter ahead — now genuinely in flight across the barrier,
// since BAR_LDS() waits lgkmcnt only. NOTE: V-register prefetch across the
// barrier is POISON (r6); V loads stay in-phase.
__global__ __launch_bounds__(256, 2) void attn_kernel(const short* __restrict__ qq,
                                                      const short* __restrict__ kb,
                                                      const short* __restrict__ vt,
                                                      const float* __restrict__ qres,
                                                      const float* __restrict__ n0w,
                                                      const float* __restrict__ n0b,
                                                      short* __restrict__ xb) {
  __shared__ short p_lds[2][64][136];  // 34.8 KB; reused as o-staging in epilogue
  int wave = threadIdx.x >> 6, lane = threadIdx.x & 63;
  int quad = lane >> 4, l16 = lane & 15;
  int b = blockIdx.x;
  int xcd = b & 7, li = b >> 3;
  int seg = xcd * 2 + (li >> 5);
  int tile = li & 31;
  int qrow0 = seg * SLQ + tile * 64;
  const short* kseg = kb + (size_t)seg * SLH * QD;
  const short* vseg = vt + (size_t)seg * HID * SLH;

  const short* qbase = qq + (size_t)(qrow0 + wave * 16 + l16) * QD + quad * 8;
  bf16x8 qf0 = *(const bf16x8*)qbase;
  bf16x8 qf1 = *(const bf16x8*)(qbase + 32);

  f32x4 o[4][4];
#pragma unroll
  for (int m = 0; m < 4; ++m)
#pragma unroll
    for (int n = 0; n < 4; ++n) o[m][n] = f32x4{0.f, 0.f, 0.f, 0.f};
  float lsum = 0.f;
  const float cexp = 0.125f * 1.44269504f;  // scale * log2(e)
  bf16x8 kpre[8][2];

#define LOADK(IT)                                                               \
  {                                                                             \
    int k0 = (IT) * 128;                                                        \
    _Pragma("unroll") for (int t = 0; t < 8; ++t) {                             \
      const short* kp = kseg + (size_t)(k0 + t * 16 + l16) * QD + quad * 8;     \
      kpre[t][0] = *(const bf16x8*)kp;                                          \
      kpre[t][1] = *(const bf16x8*)(kp + 32);                                   \
    }                                                                           \
  }

#define S_PHASE(BUF)                                                            \
  {                                                                             \
    f32x4 s[8];                                                                 \
    _Pragma("unroll") for (int t = 0; t < 8; ++t) {                             \
      f32x4 a = f32x4{0.f, 0.f, 0.f, 0.f};                                      \
      a = mfma16(kpre[t][0], qf0, a);                                           \
      a = mfma16(kpre[t][1], qf1, a);                                           \
      s[t] = a;                                                                 \
    }                                                                           \
    _Pragma("unroll") for (int t = 0; t < 8; ++t) {                             \
      float p0 = __builtin_amdgcn_exp2f(s[t][0] * cexp);                        \
      float p1 = __builtin_amdgcn_exp2f(s[t][1] * cexp);                        \
      float p2 = __builtin_amdgcn_exp2f(s[t][2] * cexp);                        \
      float p3 = __builtin_amdgcn_exp2f(s[t][3] * cexp);                        \
      lsum += (p0 + p1) + (p2 + p3);                                            \
      s16x4 pk;                                                                 \
      pk[0] = f2bf(p0); pk[1] = f2bf(p1); pk[2] = f2bf(p2); pk[3] = f2bf(p3);   \
      *(s16x4*)&p_lds[BUF][wave * 16 + l16][t * 16 + quad * 4] = pk;            \
    }                                                                           \
  }

#define PV_PHASE(IT, BUF)                                                       \
  {                                                                             \
    int k0 = (IT) * 128;                                                        \
    _Pragma("unroll") for (int ks = 0; ks < 4; ++ks) {                          \
      bf16x8 pf[4];                                                             \
      _Pragma("unroll") for (int m = 0; m < 4; ++m)                             \
        pf[m] = *(const bf16x8*)&p_lds[BUF][m * 16 + l16][ks * 32 + quad * 8];  \
      _Pragma("unroll") for (int n = 0; n < 4; ++n) {                           \
        const short* vp = vseg + (size_t)(wave * 64 + n * 16 + l16) * SLH +     \
                          k0 + ks * 32 + quad * 8;                              \
        bf16x8 vf = *(const bf16x8*)vp;                                         \
        _Pragma("unroll") for (int m = 0; m < 4; ++m)                           \
          o[m][n] = mfma16(pf[m], vf, o[m][n]);                                 \
      }                                                                         \
    }                                                                           \
  }

  LOADK(0)
  S_PHASE(0)
  LOADK(1)
  BAR_LDS();
#pragma unroll 1
  for (int it = 1; it < 16; ++it) {
    S_PHASE(it & 1)
    if (it < 15) LOADK(it + 1)
    PV_PHASE(it - 1, (it - 1) & 1)
    BAR_LDS();
  }
  PV_PHASE(15, 1)

  lsum += __shfl_xor(lsum, 16);
  lsum += __shfl_xor(lsum, 32);
  float linv = 1.f / lsum;

  BAR_LDS();  // all PV LDS reads done before o-staging overwrites p_lds
  short (*ob)[264] = (short(*)[264]) & p_lds[0][0][0];
#pragma unroll
  for (int m = 0; m < 4; ++m)
#pragma unroll
    for (int n = 0; n < 4; ++n)
#pragma unroll
      for (int r = 0; r < 4; ++r)
        ob[m * 16 + quad * 4 + r][wave * 64 + n * 16 + l16] = f2bf(o[m][n][r]);
  BAR_LDS();

  {
    int row = wave * 16 + l16;
    float y[64];
    float s1 = 0.f, s2 = 0.f;
    const float* qp = qres + (size_t)(qrow0 + row) * HID + quad * 64;
#pragma unroll
    for (int k = 0; k < 8; ++k) {
      bf16x8 ov = *(const bf16x8*)&ob[row][quad * 64 + k * 8];
      f32x4 qa = *(const f32x4*)(qp + k * 8);
      f32x4 qb = *(const f32x4*)(qp + k * 8 + 4);
#pragma unroll
      for (int j = 0; j < 4; ++j) {
        float yv = qa[j] + bf2f(ov[j]) * linv;
        y[k * 8 + j] = yv;
        s1 += yv; s2 += yv * yv;
      }
#pragma unroll
      for (int j = 0; j < 4; ++j) {
        float yv = qb[j] + bf2f(ov[4 + j]) * linv;
        y[k * 8 + 4 + j] = yv;
        s1 += yv; s2 += yv * yv;
      }
    }
    s1 += __shfl_xor(s1, 16); s2 += __shfl_xor(s2, 16);
    s1 += __shfl_xor(s1, 32); s2 += __shfl_xor(s2, 32);
    float mean = s1 * (1.f / HID);
    float var = s2 * (1.f / HID) - mean * mean;
    float rstd = rsqrtf(var + 1e-5f);
    short* xp = xb + (size_t)(qrow0 + row) * HID + quad * 64;
#pragma unroll
    for (int k = 0; k < 8; ++k) {
      f32x4 wa = *(const f32x4*)(n0w + quad * 64 + k * 8);
      f32x4 wb = *(const f32x4*)(n0w + quad * 64 + k * 8 + 4);
      f32x4 ba = *(const f32x4*)(n0b + quad * 64 + k * 8);
      f32x4 bb = *(const f32x4*)(n0b + quad * 64 + k * 8 + 4);
      s16x4 o0, o1;
#pragma unroll
      for (int j = 0; j < 4; ++j) {
        o0[j] = f2bf((y[k * 8 + j] - mean) * rstd * wa[j] + ba[j]);
        o1[j] = f2bf((y[k * 8 + 4 + j] - mean) * rstd * wb[j] + bb[j]);
      }
      *(s16x4*)(xp + k * 8) = o0;
      *(s16x4*)(xp + k * 8 + 4) = o1;
    }
  }
#undef LOADK
#undef S_PHASE
#undef PV_PHASE
}

// out = LN(x + relu(x@fc_w^T + fc_b)); x (bf16) staged via LDS — coalesced
// reads, frags via ds_read_b128, residual from LDS (no global re-read).
__global__ __launch_bounds__(256) void fc_ln_kernel(const short* __restrict__ xb,
                                                    const short* __restrict__ fwb,
                                                    const float* __restrict__ fcb,
                                                    const float* __restrict__ w1,
                                                    const float* __restrict__ b1,
                                                    float* __restrict__ out) {
  __shared__ short xt[64][264];
  int m0 = blockIdx.x * 64;
  // stage 64 rows x 256 bf16 (32 KB); each wave reads 1 KB contiguous
#pragma unroll
  for (int i = 0; i < 8; ++i) {
    int idx = i * 256 + threadIdx.x;
    int row = idx >> 5, col = (idx & 31) * 8;
    bf16x8 v = *(const bf16x8*)(xb + (size_t)(m0 + row) * HID + col);
    *(bf16x8*)&xt[row][col] = v;
  }
  __syncthreads();
  int wave = threadIdx.x >> 6, lane = threadIdx.x & 63;
  int quad = lane >> 4, l16 = lane & 15;
  int mw = wave * 16;
  f32x4 acc[16];
#pragma unroll
  for (int n = 0; n < 16; ++n) acc[n] = f32x4{0.f, 0.f, 0.f, 0.f};
#pragma unroll
  for (int ks = 0; ks < 8; ++ks) {
    bf16x8 a = *(const bf16x8*)&xt[mw + l16][ks * 32 + quad * 8];
#pragma unroll
    for (int n = 0; n < 16; ++n) {
      bf16x8 b = *(const bf16x8*)(fwb + (size_t)(n * 16 + l16) * HID + ks * 32 + quad * 8);
      acc[n] = mfma16(a, b, acc[n]);
    }
  }
#pragma unroll
  for (int r = 0; r < 4; ++r) {
    int lrow = mw + quad * 4 + r;
    int row = m0 + lrow;
    float yv[16];
    float s = 0.f, s2 = 0.f;
#pragma unroll
    for (int n = 0; n < 16; ++n) {
      int col = n * 16 + l16;
      float hres = acc[n][r] + fcb[col];
      hres = fmaxf(hres, 0.f);
      float y = bf2f(xt[lrow][col]) + hres;
      yv[n] = y;
      s += y;
      s2 += y * y;
    }
#pragma unroll
    for (int off = 1; off < 16; off <<= 1) {
      s += __shfl_xor(s, off);
      s2 += __shfl_xor(s2, off);
    }
    float mean = s * (1.f / HID);
    float var = s2 * (1.f / HID) - mean * mean;
    float rstd = rsqrtf(var + 1e-5f);
#pragma unroll
    for (int n = 0; n < 16; ++n) {
      int col = n * 16 + l16;
      out[(size_t)row * HID + col] = (yv[n] - mean) * rstd * w1[col] + b1[col];
    }
  }
}

extern "C" void kernel_launch(void* const* d_in, const int* in_sizes, int n_in,
                              void* d_out, int out_size, void* d_ws, size_t ws_size,
                              hipStream_t stream) {
  const float* q = (const float*)d_in[0];
  const float* h = (const float*)d_in[1];
  const float* WQ = (const float*)d_in[2];
  const float* WK = (const float*)d_in[3];
  const float* WV = (const float*)d_in[4];
  const float* fc_w = (const float*)d_in[5];
  const float* fc_b = (const float*)d_in[6];
  const float* n0w = (const float*)d_in[7];
  const float* n0b = (const float*)d_in[8];
  const float* n1w = (const float*)d_in[9];
  const float* n1b = (const float*)d_in[10];

  char* ws = (char*)d_ws;
  short* qq = (short*)(ws);                            //  4 MB  [0,4)
  short* kb = (short*)(ws + ((size_t)4 << 20));        //  4 MB  [4,8)
  short* vt = (short*)(ws + ((size_t)8 << 20));        // 16 MB  [8,24)
  short* xb = (short*)(ws + ((size_t)24 << 20));       // 16 MB  [24,40)
  short* wqb = (short*)(ws + ((size_t)40 << 20));
  short* wkb = (short*)(ws + ((size_t)40 << 20) + 32 * 1024);
  short* wvb = (short*)(ws + ((size_t)40 << 20) + 64 * 1024);
  short* fwb = (short*)(ws + ((size_t)40 << 20) + 192 * 1024);

  cast4_kernel<<<640, 256, 0, stream>>>(WQ, wqb, QD * HID, WK, wkb, QD * HID,
                                        WV, wvb, HID * HID, fc_w, fwb, HID * HID);
  proj_q_kernel<<<512, 256, 0, stream>>>(q, wqb, qq);
  proj_hv_kernel<<<512, 256, 0, stream>>>(h, wkb, wvb, kb, vt);
  attn_kernel<<<512, 256, 0, stream>>>(qq, kb, vt, q, n0w, n0b, xb);
  fc_ln_kernel<<<512, 256, 0, stream>>>(xb, fwb, fc_b, n1w, n1b, (float*)d_out);
}